// Round 3
// baseline (255.462 us; speedup 1.0000x reference)
//
#include <hip/hip_runtime.h>
#include <hip/hip_bf16.h>

#define BB 4
#define NN 2048
#define NH 4
#define HDD 16
#define FD 64
#define SPLIT 4
#define KPB (NN / SPLIT)
#define L2E 1.44269504088896f

typedef __attribute__((ext_vector_type(8))) short bf16x8;
typedef __attribute__((ext_vector_type(4))) float f32x4;

union BW { __hip_bfloat16 b; unsigned short u; };

static __device__ inline unsigned pk2(float a, float b) {
    BW x, y;
    x.b = __float2bfloat16(a);
    y.b = __float2bfloat16(b);
    return (unsigned)x.u | ((unsigned)y.u << 16);
}

static __device__ inline float wsum(float v) {
    v += __shfl_xor(v, 1);  v += __shfl_xor(v, 2);  v += __shfl_xor(v, 4);
    v += __shfl_xor(v, 8);  v += __shfl_xor(v, 16); v += __shfl_xor(v, 32);
    return v;
}

// ---------------- Pass 0: fold the compress/expand pairs into single matrices.
// W1 = Wqc @ Wqe  [64,192] (q-cols pre-scaled by 0.25/ln2), b1 = bqc @ Wqe + bqe
// W2 = Woc @ Woe  [64,64],  b2 = boc @ Woe + boe
__global__ __launch_bounds__(256) void fuse_kernel(
    const float* __restrict__ Wqc, const float* __restrict__ bqc,
    const float* __restrict__ Wqe, const float* __restrict__ bqe,
    const float* __restrict__ Woc, const float* __restrict__ boc,
    const float* __restrict__ Woe, const float* __restrict__ boe,
    float* __restrict__ W1, float* __restrict__ b1,
    float* __restrict__ W2, float* __restrict__ b2)
{
    const int t = threadIdx.x;
    if (blockIdx.x == 0) {
        for (int idx = t; idx < 64 * 192; idx += 256) {
            const int r = idx / 192, c = idx - r * 192;
            float a = 0.f;
            #pragma unroll
            for (int j = 0; j < 24; ++j) a += Wqc[r * 24 + j] * Wqe[j * 192 + c];
            if (c < 64) a *= 0.25f * L2E;
            W1[idx] = a;
        }
        if (t < 192) {
            float a = bqe[t];
            #pragma unroll
            for (int j = 0; j < 24; ++j) a += bqc[j] * Wqe[j * 192 + t];
            if (t < 64) a *= 0.25f * L2E;
            b1[t] = a;
        }
    } else {
        for (int idx = t; idx < 64 * 64; idx += 256) {
            const int r = idx >> 6, c = idx & 63;
            float a = 0.f;
            #pragma unroll
            for (int j = 0; j < 8; ++j) a += Woc[r * 8 + j] * Woe[j * 64 + c];
            W2[idx] = a;
        }
        if (t < 64) {
            float a = boe[t];
            #pragma unroll
            for (int j = 0; j < 8; ++j) a += boc[j] * Woe[j * 64 + t];
            b2[t] = a;
        }
    }
}

// ---------------- Pass A: qkv = feat @ W1 + b1 -> Q_ext/K_ext/Vt (bf16)
// One wave per node, 4 nodes per block. All 64 lanes busy: lane owns 3 outputs.
// Q_ext row (32): [ q*0.25/ln2 (16) | bf1[h,n,:]/ln2 (8) | 0 (8) ]
// K_ext row (32): [ k           (16) | bf2[h,:,n]     (8) | 0 (8) ]
// Vt[b][h][d][n] = v
__global__ __launch_bounds__(256) void qkv_kernel(
    const float* __restrict__ feat,
    const float* __restrict__ W1, const float* __restrict__ b1,
    const float* __restrict__ bf1, const float* __restrict__ bf2,
    __hip_bfloat16* __restrict__ Qe, __hip_bfloat16* __restrict__ Ke,
    __hip_bfloat16* __restrict__ Vt)
{
    __shared__ float fl[4][64];
    const int t = threadIdx.x;
    const int w = t >> 6, lane = t & 63;
    const int bn = blockIdx.x * 4 + w;
    const int b = bn >> 11, n = bn & (NN - 1);

    fl[w][lane] = feat[(size_t)bn * FD + lane];
    __syncthreads();

    float v0 = b1[lane], v1 = b1[lane + 64], v2 = b1[lane + 128];
    #pragma unroll 8
    for (int d = 0; d < 64; ++d) {
        const float f = fl[w][d];
        v0 += f * W1[d * 192 + lane];
        v1 += f * W1[d * 192 + 64 + lane];
        v2 += f * W1[d * 192 + 128 + lane];
    }

    const int h = lane >> 4, hi = lane & 15;
    const size_t rowQ = (((size_t)b * NH + h) * NN + n) * 32;
    Qe[rowQ + hi] = __float2bfloat16(v0);            // scale pre-folded into W1/b1
    Ke[rowQ + hi] = __float2bfloat16(v1);
    Vt[(((size_t)b * NH + h) * HDD + hi) * NN + n] = __float2bfloat16(v2);

    // bias-factor extension + zero padding
    if (lane < 32) {
        const int hh = lane >> 3, c = lane & 7;
        const size_t r = (((size_t)b * NH + hh) * NN + n) * 32;
        Qe[r + 16 + c] = __float2bfloat16(bf1[((size_t)hh * NN + n) * 8 + c] * L2E);
        Qe[r + 24 + c] = __float2bfloat16(0.f);
    } else {
        const int hh = (lane - 32) >> 3, c = lane & 7;
        const size_t r = (((size_t)b * NH + hh) * NN + n) * 32;
        Ke[r + 16 + c] = __float2bfloat16(bf2[((size_t)hh * 8 + c) * NN + n]);
        Ke[r + 24 + c] = __float2bfloat16(0.f);
    }
}

// ---------------- Pass B: fused attention, split-K, max-free softmax, barrier-free.
// Block = (b, 16-query tile, key-split), 4 independent waves = 4 heads.
// S^T = mfma(K_ext permuted-rows, Q_ext): lane(ql,g) holds keys 8g..8g+7 of each
// 32-key chunk -> P already in x32 B-fragment layout -> single PV mfma, no shuffles.
// Graph values loaded straight to registers (2x float4 per graph) - no LDS, no barriers.
__global__ __launch_bounds__(256, 6) void attn_kernel(
    const float* __restrict__ fixedg, const float* __restrict__ learng,
    const float* __restrict__ gfus,
    const __hip_bfloat16* __restrict__ Qe, const __hip_bfloat16* __restrict__ Ke,
    const __hip_bfloat16* __restrict__ Vt,
    float* __restrict__ pacc, float* __restrict__ psum)
{
    __shared__ float ldsO[16][68];       // output transpose buffer only

    const int bid = blockIdx.x;
    const int split = bid & (SPLIT - 1);
    const int qt = (bid >> 2) & 127;
    const int b = bid >> 9;
    const int qb = qt << 4;
    const int kbase = split * KPB;
    const int t = threadIdx.x;
    const int hw = t >> 6;               // head
    const int lane = t & 63;
    const int ql = lane & 15;            // query within tile / V dim row
    const int g  = lane >> 4;            // 16-lane group

    const float sg = 1.f / (1.f + __expf(-gfus[0]));
    const float fre = sg * L2E, ofre = (1.f - sg) * L2E;   // exp2-folded blend

    const size_t bhN = ((size_t)b * NH + hw) * NN;
    const bf16x8 qf = *(const bf16x8*)(Qe + (bhN + qb + ql) * 32 + g * 8);
    const __hip_bfloat16* kptr = Ke + bhN * 32;
    const __hip_bfloat16* vbase = Vt + (((size_t)b * NH + hw) * HDD + ql) * NN;
    const int krow = 8 * (ql >> 2) + (ql & 3);   // permuted key row within chunk

    // this lane's graph rows (row = query qb+ql), offset to this split's keys
    const float* lrow = learng + ((size_t)b * NN + qb + ql) * NN + kbase;
    const float* frow = fixedg + (size_t)(qb + ql) * NN + kbase;

    float ssum = 0.f;
    f32x4 acc = {0.f, 0.f, 0.f, 0.f};

    #pragma unroll 2
    for (int kt = 0; kt < KPB / 64; ++kt) {
        #pragma unroll
        for (int hf = 0; hf < 2; ++hf) {
            const int co = kt * 64 + hf * 32 + 8 * g;   // this lane's 8 keys
            const f32x4 l0 = *(const f32x4*)(lrow + co);
            const f32x4 l1 = *(const f32x4*)(lrow + co + 4);
            const f32x4 f0 = *(const f32x4*)(frow + co);
            const f32x4 f1 = *(const f32x4*)(frow + co + 4);
            const int kb = kbase + kt * 64 + hf * 32;
            const bf16x8 k0 = *(const bf16x8*)(kptr + (size_t)(kb + krow) * 32 + g * 8);
            const bf16x8 k1 = *(const bf16x8*)(kptr + (size_t)(kb + 4 + krow) * 32 + g * 8);
            const f32x4 z = {0.f, 0.f, 0.f, 0.f};
            f32x4 c0 = __builtin_amdgcn_mfma_f32_16x16x32_bf16(k0, qf, z, 0, 0, 0);
            f32x4 c1 = __builtin_amdgcn_mfma_f32_16x16x32_bf16(k1, qf, z, 0, 0, 0);
            #pragma unroll
            for (int j = 0; j < 4; ++j) {
                c0[j] = __builtin_amdgcn_exp2f(c0[j] + fre * l0[j] + ofre * f0[j]);
                c1[j] = __builtin_amdgcn_exp2f(c1[j] + fre * l1[j] + ofre * f1[j]);
                ssum += c0[j] + c1[j];
            }
            union { unsigned u[4]; bf16x8 v; } pf;
            pf.u[0] = pk2(c0[0], c0[1]);
            pf.u[1] = pk2(c0[2], c0[3]);
            pf.u[2] = pk2(c1[0], c1[1]);
            pf.u[3] = pk2(c1[2], c1[3]);
            const bf16x8 vf = *(const bf16x8*)(vbase + kb + 8 * g);
            acc = __builtin_amdgcn_mfma_f32_16x16x32_bf16(vf, pf.v, acc, 0, 0, 0);
        }
    }

    // per-query sum of exps
    ssum += __shfl_xor(ssum, 16);
    ssum += __shfl_xor(ssum, 32);
    if (g == 0)
        psum[((size_t)(split * BB + b) * NH + hw) * NN + qb + ql] = ssum;

    // unnormalized partial context -> transpose via LDS -> coalesced writes
    #pragma unroll
    for (int j = 0; j < 4; ++j) ldsO[ql][hw * 16 + 4 * g + j] = acc[j];
    __syncthreads();
    for (int q2 = hw; q2 < 16; q2 += 4)
        pacc[((size_t)(split * BB + b) * NN + qb + q2) * FD + lane] = ldsO[q2][lane];
}

// ---------------- Pass C: combine splits, out = LN(ctx @ W2 + b2 + residual)
__global__ __launch_bounds__(256) void out_kernel(
    const float* __restrict__ pacc, const float* __restrict__ psum,
    const float* __restrict__ feat,
    const float* __restrict__ W2, const float* __restrict__ b2,
    const float* __restrict__ lng, const float* __restrict__ lnb,
    float* __restrict__ out)
{
    __shared__ float cl[4][64];
    const int t = threadIdx.x;
    const int w = t >> 6, d = t & 63;
    const int node = blockIdx.x * 4 + w;
    const int b = node >> 11, n = node & (NN - 1);
    const int h = d >> 4;

    float a = 0.f, sh = 0.f;
    #pragma unroll
    for (int sp = 0; sp < SPLIT; ++sp) {
        a  += pacc[((size_t)sp * BB * NN + node) * FD + d];
        sh += psum[((size_t)(sp * BB + b) * NH + h) * NN + n];
    }
    cl[w][d] = a / sh;
    __syncthreads();

    float o = b2[d];
    #pragma unroll 8
    for (int dd = 0; dd < 64; ++dd) o += cl[w][dd] * W2[dd * 64 + d];
    o += feat[(size_t)node * FD + d];

    const float mu = wsum(o) * (1.f / 64.f);
    const float df = o - mu;
    const float va = wsum(df * df) * (1.f / 64.f);
    out[(size_t)node * FD + d] = df * rsqrtf(va + 1e-5f) * lng[d] + lnb[d];
    if (blockIdx.x == 0 && t == 0)
        out[(size_t)BB * NN * FD] = 4.8828125e-9f;  // 1e-5 * mean(attn) = 1e-5 / N exactly
}

extern "C" void kernel_launch(void* const* d_in, const int* in_sizes, int n_in,
                              void* d_out, int out_size, void* d_ws, size_t ws_size,
                              hipStream_t stream) {
    const float* feat   = (const float*)d_in[0];
    const float* fixedg = (const float*)d_in[1];
    const float* learng = (const float*)d_in[2];
    const float* Wqc = (const float*)d_in[3];
    const float* bqc = (const float*)d_in[4];
    const float* Wqe = (const float*)d_in[5];
    const float* bqe = (const float*)d_in[6];
    const float* Woc = (const float*)d_in[7];
    const float* boc = (const float*)d_in[8];
    const float* Woe = (const float*)d_in[9];
    const float* boe = (const float*)d_in[10];
    const float* bf1 = (const float*)d_in[11];
    const float* bf2 = (const float*)d_in[12];
    const float* gfus = (const float*)d_in[13];
    const float* lng = (const float*)d_in[14];
    const float* lnb = (const float*)d_in[15];

    char* ws = (char*)d_ws;
    __hip_bfloat16* Qe = (__hip_bfloat16*)ws;                       // 2 MB
    __hip_bfloat16* Ke = Qe + (size_t)BB * NH * NN * 32;            // 2 MB
    __hip_bfloat16* Vt = Ke + (size_t)BB * NH * NN * 32;            // 1 MB
    float* pacc = (float*)(Vt + (size_t)BB * NH * HDD * NN);        // 8 MB
    float* psum = pacc + (size_t)SPLIT * BB * NN * FD;              // 512 KB
    float* W1 = psum + (size_t)SPLIT * BB * NH * NN;                // 48 KB
    float* b1 = W1 + 64 * 192;
    float* W2 = b1 + 192;                                           // 16 KB
    float* b2 = W2 + 64 * 64;
    float* out = (float*)d_out;

    hipLaunchKernelGGL(fuse_kernel, dim3(2), dim3(256), 0, stream,
                       Wqc, bqc, Wqe, bqe, Woc, boc, Woe, boe, W1, b1, W2, b2);
    hipLaunchKernelGGL(qkv_kernel, dim3(BB * NN / 4), dim3(256), 0, stream,
                       feat, W1, b1, bf1, bf2, Qe, Ke, Vt);
    hipLaunchKernelGGL(attn_kernel, dim3(BB * (NN / 16) * SPLIT), dim3(256), 0, stream,
                       fixedg, learng, gfus, Qe, Ke, Vt, pacc, psum);
    hipLaunchKernelGGL(out_kernel, dim3(BB * NN / 4), dim3(256), 0, stream,
                       pacc, psum, feat, W2, b2, lng, lnb, out);
}

// Round 5
// 216.876 us; speedup vs baseline: 1.1779x; 1.1779x over previous
//
#include <hip/hip_runtime.h>
#include <hip/hip_bf16.h>

#define BB 4
#define NN 2048
#define NH 4
#define HDD 16
#define FD 64
#define SPLIT 8
#define KPB (NN / SPLIT)      // 256 keys per split
#define KT (KPB / 64)         // 4 tiles of 64 keys
#define PADK 17               // odd stride: staging writes/reads <=2-way (free)
#define L2E 1.44269504088896f

typedef __attribute__((ext_vector_type(8))) short bf16x8;
typedef __attribute__((ext_vector_type(4))) float f32x4;

union BW { __hip_bfloat16 b; unsigned short u; };

static __device__ inline unsigned pk2(float a, float b) {
    BW x, y;
    x.b = __float2bfloat16(a);
    y.b = __float2bfloat16(b);
    return (unsigned)x.u | ((unsigned)y.u << 16);
}

static __device__ inline float wsum(float v) {
    v += __shfl_xor(v, 1);  v += __shfl_xor(v, 2);  v += __shfl_xor(v, 4);
    v += __shfl_xor(v, 8);  v += __shfl_xor(v, 16); v += __shfl_xor(v, 32);
    return v;
}

// ---------------- Pass 0: fold the compress/expand pairs into single matrices.
// W1 = Wqc @ Wqe  [64,192] (q-cols pre-scaled by 0.25/ln2), b1 = bqc @ Wqe + bqe
// W2 = Woc @ Woe  [64,64],  b2 = boc @ Woe + boe
__global__ __launch_bounds__(256) void fuse_kernel(
    const float* __restrict__ Wqc, const float* __restrict__ bqc,
    const float* __restrict__ Wqe, const float* __restrict__ bqe,
    const float* __restrict__ Woc, const float* __restrict__ boc,
    const float* __restrict__ Woe, const float* __restrict__ boe,
    float* __restrict__ W1, float* __restrict__ b1,
    float* __restrict__ W2, float* __restrict__ b2)
{
    const int t = threadIdx.x;
    if (blockIdx.x == 0) {
        for (int idx = t; idx < 64 * 192; idx += 256) {
            const int r = idx / 192, c = idx - r * 192;
            float a = 0.f;
            #pragma unroll
            for (int j = 0; j < 24; ++j) a += Wqc[r * 24 + j] * Wqe[j * 192 + c];
            if (c < 64) a *= 0.25f * L2E;
            W1[idx] = a;
        }
        if (t < 192) {
            float a = bqe[t];
            #pragma unroll
            for (int j = 0; j < 24; ++j) a += bqc[j] * Wqe[j * 192 + t];
            if (t < 64) a *= 0.25f * L2E;
            b1[t] = a;
        }
    } else {
        for (int idx = t; idx < 64 * 64; idx += 256) {
            const int r = idx >> 6, c = idx & 63;
            float a = 0.f;
            #pragma unroll
            for (int j = 0; j < 8; ++j) a += Woc[r * 8 + j] * Woe[j * 64 + c];
            W2[idx] = a;
        }
        if (t < 64) {
            float a = boe[t];
            #pragma unroll
            for (int j = 0; j < 8; ++j) a += boc[j] * Woe[j * 64 + t];
            b2[t] = a;
        }
    }
}

// ---------------- Pass A: qkv = feat @ W1 + b1 -> Q_ext/K_ext/Vt (bf16)
// One wave per node, 4 nodes per block.
// Q_ext row (32): [ q*0.25/ln2 (16) | bf1[h,n,:]/ln2 (8) | 0 (8) ]
// K_ext row (32): [ k           (16) | bf2[h,:,n]     (8) | 0 (8) ]
// Vt[b][h][d][n] = v
__global__ __launch_bounds__(256) void qkv_kernel(
    const float* __restrict__ feat,
    const float* __restrict__ W1, const float* __restrict__ b1,
    const float* __restrict__ bf1, const float* __restrict__ bf2,
    __hip_bfloat16* __restrict__ Qe, __hip_bfloat16* __restrict__ Ke,
    __hip_bfloat16* __restrict__ Vt)
{
    __shared__ float fl[4][64];
    const int t = threadIdx.x;
    const int w = t >> 6, lane = t & 63;
    const int bn = blockIdx.x * 4 + w;
    const int b = bn >> 11, n = bn & (NN - 1);

    fl[w][lane] = feat[(size_t)bn * FD + lane];
    __syncthreads();

    float v0 = b1[lane], v1 = b1[lane + 64], v2 = b1[lane + 128];
    #pragma unroll 8
    for (int d = 0; d < 64; ++d) {
        const float f = fl[w][d];
        v0 += f * W1[d * 192 + lane];
        v1 += f * W1[d * 192 + 64 + lane];
        v2 += f * W1[d * 192 + 128 + lane];
    }

    const int h = lane >> 4, hi = lane & 15;
    const size_t rowQ = (((size_t)b * NH + h) * NN + n) * 32;
    Qe[rowQ + hi] = __float2bfloat16(v0);            // scale pre-folded into W1/b1
    Ke[rowQ + hi] = __float2bfloat16(v1);
    Vt[(((size_t)b * NH + h) * HDD + hi) * NN + n] = __float2bfloat16(v2);

    // bias-factor extension + zero padding
    if (lane < 32) {
        const int hh = lane >> 3, c = lane & 7;
        const size_t r = (((size_t)b * NH + hh) * NN + n) * 32;
        Qe[r + 16 + c] = __float2bfloat16(bf1[((size_t)hh * NN + n) * 8 + c] * L2E);
        Qe[r + 24 + c] = __float2bfloat16(0.f);
    } else {
        const int hh = (lane - 32) >> 3, c = lane & 7;
        const size_t r = (((size_t)b * NH + hh) * NN + n) * 32;
        Ke[r + 16 + c] = __float2bfloat16(bf2[((size_t)hh * 8 + c) * NN + n]);
        Ke[r + 24 + c] = __float2bfloat16(0.f);
    }
}

// ---------------- Pass B: fused attention, split-K, max-free softmax.
// Block = (b, 16-query tile, key-split), 4 waves = 4 heads.
// Graph tiles staged in LDS with coalesced float4 loads; register-prefetch one
// tile ahead (T14: issue early / blend+write late); ONE barrier per 64-key
// tile via double-buffered LDS (write(kt) vs read(kt-2) separated by barrier(kt-1)).
// S^T = mfma(K permuted-rows, Q): lane(ql,g) holds keys 8g..8g+7 of each 32-key
// chunk -> P already in x32 B-fragment layout -> single PV mfma, no shuffles.
__global__ __launch_bounds__(256, 8) void attn_kernel(
    const float* __restrict__ fixedg, const float* __restrict__ learng,
    const float* __restrict__ gfus,
    const __hip_bfloat16* __restrict__ Qe, const __hip_bfloat16* __restrict__ Ke,
    const __hip_bfloat16* __restrict__ Vt,
    float* __restrict__ pacc, float* __restrict__ psum)
{
    __shared__ float lds[2 * 64 * PADK];   // staging dbuf; buf0 (1088 f) reused as ldsO[16][68]

    const int bid = blockIdx.x;
    const int split = bid & (SPLIT - 1);
    const int qt = (bid >> 3) & 127;
    const int b = bid >> 10;
    const int qb = qt << 4;
    const int kbase = split * KPB;
    const int t = threadIdx.x;
    const int hw = t >> 6;               // head
    const int lane = t & 63;
    const int ql = lane & 15;            // query within tile / V dim row
    const int g  = lane >> 4;            // 16-lane group

    const float sg = 1.f / (1.f + __expf(-gfus[0]));
    const float fre = sg * L2E, ofre = (1.f - sg) * L2E;   // exp2-folded blend

    const size_t bhN = ((size_t)b * NH + hw) * NN;
    const bf16x8 qf = *(const bf16x8*)(Qe + (bhN + qb + ql) * 32 + g * 8);
    const __hip_bfloat16* kptr = Ke + bhN * 32;
    const __hip_bfloat16* vbase = Vt + (((size_t)b * NH + hw) * HDD + ql) * NN;
    const int krow = 8 * (ql >> 2) + (ql & 3);   // permuted key row within chunk

    // staging role: thread t loads row sq, 4 cols at sk (coalesced f4 per 8 lanes/row)
    const int sq = t >> 4;               // 0..15 query row
    const int sk = (t & 15) * 4;         // col group within 64-key tile
    const float* lrow = learng + ((size_t)b * NN + qb + sq) * NN + kbase + sk;
    const float* frow = fixedg + ((size_t)(qb + sq)) * NN + kbase + sk;

    float ssum = 0.f;
    f32x4 acc = {0.f, 0.f, 0.f, 0.f};

    f32x4 lw[2], fw[2];
    lw[0] = *(const f32x4*)(lrow);       // prefetch tile 0
    fw[0] = *(const f32x4*)(frow);

    #pragma unroll
    for (int kt = 0; kt < KT; ++kt) {
        const int cur = kt & 1, nxt = cur ^ 1;
        if (kt + 1 < KT) {               // issue next tile's loads first (stay in flight)
            lw[nxt] = *(const f32x4*)(lrow + (kt + 1) * 64);
            fw[nxt] = *(const f32x4*)(frow + (kt + 1) * 64);
        }
        // blend current tile (loads issued a full compute-phase ago) -> LDS
        float* dst = lds + cur * (64 * PADK);
        #pragma unroll
        for (int i = 0; i < 4; ++i)
            dst[(sk + i) * PADK + sq] = fre * lw[cur][i] + ofre * fw[cur][i];
        __syncthreads();

        const float* cmb = lds + cur * (64 * PADK);
        #pragma unroll
        for (int hf = 0; hf < 2; ++hf) {
            const int kb = kbase + kt * 64 + hf * 32;
            const bf16x8 k0 = *(const bf16x8*)(kptr + (size_t)(kb + krow) * 32 + g * 8);
            const bf16x8 k1 = *(const bf16x8*)(kptr + (size_t)(kb + 4 + krow) * 32 + g * 8);
            const f32x4 z = {0.f, 0.f, 0.f, 0.f};
            f32x4 c0 = __builtin_amdgcn_mfma_f32_16x16x32_bf16(k0, qf, z, 0, 0, 0);
            f32x4 c1 = __builtin_amdgcn_mfma_f32_16x16x32_bf16(k1, qf, z, 0, 0, 0);
            const int lk = hf * 32 + 8 * g;
            #pragma unroll
            for (int j = 0; j < 4; ++j) {
                c0[j] = __builtin_amdgcn_exp2f(c0[j] + cmb[(lk + j) * PADK + ql]);
                c1[j] = __builtin_amdgcn_exp2f(c1[j] + cmb[(lk + 4 + j) * PADK + ql]);
                ssum += c0[j] + c1[j];
            }
            union { unsigned u[4]; bf16x8 v; } pf;
            pf.u[0] = pk2(c0[0], c0[1]);
            pf.u[1] = pk2(c0[2], c0[3]);
            pf.u[2] = pk2(c1[0], c1[1]);
            pf.u[3] = pk2(c1[2], c1[3]);
            const bf16x8 vf = *(const bf16x8*)(vbase + kb + 8 * g);
            acc = __builtin_amdgcn_mfma_f32_16x16x32_bf16(vf, pf.v, acc, 0, 0, 0);
        }
    }

    // per-query sum of exps
    ssum += __shfl_xor(ssum, 16);
    ssum += __shfl_xor(ssum, 32);
    if (g == 0)
        psum[((size_t)(split * BB + b) * NH + hw) * NN + qb + ql] = ssum;

    // unnormalized partial context -> transpose via buf0-as-ldsO (safe: last buf0
    // read was kt=KT-2, fenced by barrier(kt=KT-1); buf1 still in use is disjoint)
    float* ldsO = lds;                    // [16][68]
    #pragma unroll
    for (int j = 0; j < 4; ++j) ldsO[ql * 68 + hw * 16 + 4 * g + j] = acc[j];
    __syncthreads();
    for (int q2 = hw; q2 < 16; q2 += 4)
        pacc[((size_t)(split * BB + b) * NN + qb + q2) * FD + lane] = ldsO[q2 * 68 + lane];
}

// ---------------- Pass C: combine splits, out = LN(ctx @ W2 + b2 + residual)
__global__ __launch_bounds__(256) void out_kernel(
    const float* __restrict__ pacc, const float* __restrict__ psum,
    const float* __restrict__ feat,
    const float* __restrict__ W2, const float* __restrict__ b2,
    const float* __restrict__ lng, const float* __restrict__ lnb,
    float* __restrict__ out)
{
    __shared__ float cl[4][64];
    const int t = threadIdx.x;
    const int w = t >> 6, d = t & 63;
    const int node = blockIdx.x * 4 + w;
    const int b = node >> 11, n = node & (NN - 1);
    const int h = d >> 4;

    float a = 0.f, sh = 0.f;
    #pragma unroll
    for (int sp = 0; sp < SPLIT; ++sp) {
        a  += pacc[((size_t)sp * BB * NN + node) * FD + d];
        sh += psum[((size_t)(sp * BB + b) * NH + h) * NN + n];
    }
    cl[w][d] = a / sh;
    __syncthreads();

    float o = b2[d];
    #pragma unroll 8
    for (int dd = 0; dd < 64; ++dd) o += cl[w][dd] * W2[dd * 64 + d];
    o += feat[(size_t)node * FD + d];

    const float mu = wsum(o) * (1.f / 64.f);
    const float df = o - mu;
    const float va = wsum(df * df) * (1.f / 64.f);
    out[(size_t)node * FD + d] = df * rsqrtf(va + 1e-5f) * lng[d] + lnb[d];
    if (blockIdx.x == 0 && t == 0)
        out[(size_t)BB * NN * FD] = 4.8828125e-9f;  // 1e-5 * mean(attn) = 1e-5 / N exactly
}

extern "C" void kernel_launch(void* const* d_in, const int* in_sizes, int n_in,
                              void* d_out, int out_size, void* d_ws, size_t ws_size,
                              hipStream_t stream) {
    const float* feat   = (const float*)d_in[0];
    const float* fixedg = (const float*)d_in[1];
    const float* learng = (const float*)d_in[2];
    const float* Wqc = (const float*)d_in[3];
    const float* bqc = (const float*)d_in[4];
    const float* Wqe = (const float*)d_in[5];
    const float* bqe = (const float*)d_in[6];
    const float* Woc = (const float*)d_in[7];
    const float* boc = (const float*)d_in[8];
    const float* Woe = (const float*)d_in[9];
    const float* boe = (const float*)d_in[10];
    const float* bf1 = (const float*)d_in[11];
    const float* bf2 = (const float*)d_in[12];
    const float* gfus = (const float*)d_in[13];
    const float* lng = (const float*)d_in[14];
    const float* lnb = (const float*)d_in[15];

    char* ws = (char*)d_ws;
    __hip_bfloat16* Qe = (__hip_bfloat16*)ws;                       // 2 MB
    __hip_bfloat16* Ke = Qe + (size_t)BB * NH * NN * 32;            // 2 MB
    __hip_bfloat16* Vt = Ke + (size_t)BB * NH * NN * 32;            // 1 MB
    float* pacc = (float*)(Vt + (size_t)BB * NH * HDD * NN);        // SPLIT*B*N*64 f32 = 16.8 MB
    float* psum = pacc + (size_t)SPLIT * BB * NN * FD;              // 1 MB
    float* W1 = psum + (size_t)SPLIT * BB * NH * NN;                // 48 KB
    float* b1 = W1 + 64 * 192;
    float* W2 = b1 + 192;                                           // 16 KB
    float* b2 = W2 + 64 * 64;
    float* out = (float*)d_out;

    hipLaunchKernelGGL(fuse_kernel, dim3(2), dim3(256), 0, stream,
                       Wqc, bqc, Wqe, bqe, Woc, boc, Woe, boe, W1, b1, W2, b2);
    hipLaunchKernelGGL(qkv_kernel, dim3(BB * NN / 4), dim3(256), 0, stream,
                       feat, W1, b1, bf1, bf2, Qe, Ke, Vt);
    hipLaunchKernelGGL(attn_kernel, dim3(BB * (NN / 16) * SPLIT), dim3(256), 0, stream,
                       fixedg, learng, gfus, Qe, Ke, Vt, pacc, psum);
    hipLaunchKernelGGL(out_kernel, dim3(BB * NN / 4), dim3(256), 0, stream,
                       pacc, psum, feat, W2, b2, lng, lnb, out);
}

// Round 7
// 206.367 us; speedup vs baseline: 1.2379x; 1.0509x over previous
//
#include <hip/hip_runtime.h>
#include <hip/hip_bf16.h>

#define BB 4
#define NN 2048
#define NH 4
#define HDD 16
#define FD 64
#define QB 32                 // queries per block
#define SPLIT 8
#define KPB (NN / SPLIT)      // 256 keys per split
#define KT (KPB / 64)         // 4 tiles of 64 keys
#define CS 68                 // graph LDS row stride (floats): 16B-aligned, <=2-way banks
#define L2E 1.44269504088896f

typedef __attribute__((ext_vector_type(8))) short bf16x8;
typedef __attribute__((ext_vector_type(4))) float f32x4;

union BW { __hip_bfloat16 b; unsigned short u; };

static __device__ inline unsigned pk2(float a, float b) {
    BW x, y;
    x.b = __float2bfloat16(a);
    y.b = __float2bfloat16(b);
    return (unsigned)x.u | ((unsigned)y.u << 16);
}

static __device__ inline float wsum(float v) {
    v += __shfl_xor(v, 1);  v += __shfl_xor(v, 2);  v += __shfl_xor(v, 4);
    v += __shfl_xor(v, 8);  v += __shfl_xor(v, 16); v += __shfl_xor(v, 32);
    return v;
}

// ---------------- Pass 0: fold the compress/expand pairs into single matrices.
// W1 = Wqc @ Wqe  [64,192] (q-cols pre-scaled by 0.25/ln2), b1 = bqc @ Wqe + bqe
// W2 = Woc @ Woe  [64,64],  b2 = boc @ Woe + boe
__global__ __launch_bounds__(256) void fuse_kernel(
    const float* __restrict__ Wqc, const float* __restrict__ bqc,
    const float* __restrict__ Wqe, const float* __restrict__ bqe,
    const float* __restrict__ Woc, const float* __restrict__ boc,
    const float* __restrict__ Woe, const float* __restrict__ boe,
    float* __restrict__ W1, float* __restrict__ b1,
    float* __restrict__ W2, float* __restrict__ b2)
{
    const int t = threadIdx.x;
    if (blockIdx.x == 0) {
        for (int idx = t; idx < 64 * 192; idx += 256) {
            const int r = idx / 192, c = idx - r * 192;
            float a = 0.f;
            #pragma unroll
            for (int j = 0; j < 24; ++j) a += Wqc[r * 24 + j] * Wqe[j * 192 + c];
            if (c < 64) a *= 0.25f * L2E;
            W1[idx] = a;
        }
        if (t < 192) {
            float a = bqe[t];
            #pragma unroll
            for (int j = 0; j < 24; ++j) a += bqc[j] * Wqe[j * 192 + t];
            if (t < 64) a *= 0.25f * L2E;
            b1[t] = a;
        }
    } else {
        for (int idx = t; idx < 64 * 64; idx += 256) {
            const int r = idx >> 6, c = idx & 63;
            float a = 0.f;
            #pragma unroll
            for (int j = 0; j < 8; ++j) a += Woc[r * 8 + j] * Woe[j * 64 + c];
            W2[idx] = a;
        }
        if (t < 64) {
            float a = boe[t];
            #pragma unroll
            for (int j = 0; j < 8; ++j) a += boc[j] * Woe[j * 64 + t];
            b2[t] = a;
        }
    }
}

// ---------------- Pass A: qkv = feat @ W1 + b1 -> Q_ext/K_ext/Vt (bf16)
// One wave per node, 4 nodes per block.
// Q_ext row (32): [ q*0.25/ln2 (16) | bf1[h,n,:]/ln2 (8) | 0 (8) ]
// K_ext row (32): [ k           (16) | bf2[h,:,n]     (8) | 0 (8) ]
// Vt[b][h][d][n] = v
__global__ __launch_bounds__(256) void qkv_kernel(
    const float* __restrict__ feat,
    const float* __restrict__ W1, const float* __restrict__ b1,
    const float* __restrict__ bf1, const float* __restrict__ bf2,
    __hip_bfloat16* __restrict__ Qe, __hip_bfloat16* __restrict__ Ke,
    __hip_bfloat16* __restrict__ Vt)
{
    __shared__ float fl[4][64];
    const int t = threadIdx.x;
    const int w = t >> 6, lane = t & 63;
    const int bn = blockIdx.x * 4 + w;
    const int b = bn >> 11, n = bn & (NN - 1);

    fl[w][lane] = feat[(size_t)bn * FD + lane];
    __syncthreads();

    float v0 = b1[lane], v1 = b1[lane + 64], v2 = b1[lane + 128];
    #pragma unroll 8
    for (int d = 0; d < 64; ++d) {
        const float f = fl[w][d];
        v0 += f * W1[d * 192 + lane];
        v1 += f * W1[d * 192 + 64 + lane];
        v2 += f * W1[d * 192 + 128 + lane];
    }

    const int h = lane >> 4, hi = lane & 15;
    const size_t rowQ = (((size_t)b * NH + h) * NN + n) * 32;
    Qe[rowQ + hi] = __float2bfloat16(v0);            // scale pre-folded into W1/b1
    Ke[rowQ + hi] = __float2bfloat16(v1);
    Vt[(((size_t)b * NH + h) * HDD + hi) * NN + n] = __float2bfloat16(v2);

    // bias-factor extension + zero padding
    if (lane < 32) {
        const int hh = lane >> 3, c = lane & 7;
        const size_t r = (((size_t)b * NH + hh) * NN + n) * 32;
        Qe[r + 16 + c] = __float2bfloat16(bf1[((size_t)hh * NN + n) * 8 + c] * L2E);
        Qe[r + 24 + c] = __float2bfloat16(0.f);
    } else {
        const int hh = (lane - 32) >> 3, c = lane & 7;
        const size_t r = (((size_t)b * NH + hh) * NN + n) * 32;
        Ke[r + 16 + c] = __float2bfloat16(bf2[((size_t)hh * 8 + c) * NN + n]);
        Ke[r + 24 + c] = __float2bfloat16(0.f);
    }
}

// ---------------- Pass B: fused attention, split-K, max-free softmax.
// Block = (b, 32-query tile, key-split); 4 waves = 4 heads; each wave owns TWO
// 16-query fragments (A: qb..qb+15, B: qb+16..qb+31) -> every K/V load feeds 2 MFMAs.
// T14 staging: graph loads issued right after the barrier, blended+written to the
// OTHER LDS buffer at the end of the compute phase (latency hidden under MFMAs).
// S^T = mfma(K permuted-rows, Q): lane(ql,g) holds keys 8g..8g+7 of each 32-key
// chunk -> P already in x32 B-fragment layout -> single PV mfma, no shuffles.
__global__ __launch_bounds__(256, 4) void attn_kernel(
    const float* __restrict__ fixedg, const float* __restrict__ learng,
    const float* __restrict__ gfus,
    const __hip_bfloat16* __restrict__ Qe, const __hip_bfloat16* __restrict__ Ke,
    const __hip_bfloat16* __restrict__ Vt,
    float* __restrict__ pacc, float* __restrict__ psum)
{
    __shared__ float lds[2 * QB * CS];   // 2 x 8704 B; buf0 reused as ldsO[32][68]

    const int bid = blockIdx.x;
    const int split = bid & (SPLIT - 1);
    const int qt = (bid >> 3) & 63;
    const int b = bid >> 9;
    const int qb = qt << 5;
    const int kbase = split * KPB;
    const int t = threadIdx.x;
    const int hw = t >> 6;               // head
    const int lane = t & 63;
    const int ql = lane & 15;            // query-within-fragment / C col
    const int g  = lane >> 4;            // 16-lane group

    const float sg = 1.f / (1.f + __expf(-gfus[0]));
    const float fre = sg * L2E, ofre = (1.f - sg) * L2E;   // exp2-folded blend

    const size_t bhN = ((size_t)b * NH + hw) * NN;
    const bf16x8 qfA = *(const bf16x8*)(Qe + (bhN + qb + ql) * 32 + g * 8);
    const bf16x8 qfB = *(const bf16x8*)(Qe + (bhN + qb + 16 + ql) * 32 + g * 8);
    const __hip_bfloat16* kptr = Ke + bhN * 32;
    const __hip_bfloat16* vbase = Vt + (((size_t)b * NH + hw) * HDD + ql) * NN;
    const int krow = 8 * (ql >> 2) + (ql & 3);   // permuted key row within chunk

    // staging role: thread t loads row sq (0..31), 8 cols at sk (coalesced 256B/8 threads)
    const int sq = t >> 3;
    const int sk = (t & 7) * 8;
    const float* lrow = learng + ((size_t)b * NN + qb + sq) * NN + kbase + sk;
    const float* frow = fixedg + ((size_t)(qb + sq)) * NN + kbase + sk;

    float ssA = 0.f, ssB = 0.f;
    f32x4 accA = {0.f, 0.f, 0.f, 0.f}, accB = {0.f, 0.f, 0.f, 0.f};
    f32x4 l0, l1, f0, f1;

    // prologue: stage tile 0 into buf0
    l0 = *(const f32x4*)(lrow);      l1 = *(const f32x4*)(lrow + 4);
    f0 = *(const f32x4*)(frow);      f1 = *(const f32x4*)(frow + 4);
    *(f32x4*)&lds[sq * CS + sk]     = fre * l0 + ofre * f0;
    *(f32x4*)&lds[sq * CS + sk + 4] = fre * l1 + ofre * f1;

    #pragma unroll
    for (int kt = 0; kt < KT; ++kt) {
        __syncthreads();
        if (kt + 1 < KT) {               // issue next tile's loads; consumed end-of-phase
            l0 = *(const f32x4*)(lrow + (kt + 1) * 64);
            l1 = *(const f32x4*)(lrow + (kt + 1) * 64 + 4);
            f0 = *(const f32x4*)(frow + (kt + 1) * 64);
            f1 = *(const f32x4*)(frow + (kt + 1) * 64 + 4);
        }
        const float* cmb = lds + (kt & 1) * (QB * CS);
        #pragma unroll
        for (int hf = 0; hf < 2; ++hf) {
            const int kb = kbase + kt * 64 + hf * 32;
            const bf16x8 k0 = *(const bf16x8*)(kptr + (size_t)(kb + krow) * 32 + g * 8);
            const bf16x8 k1 = *(const bf16x8*)(kptr + (size_t)(kb + 4 + krow) * 32 + g * 8);
            const f32x4 z = {0.f, 0.f, 0.f, 0.f};
            f32x4 cA0 = __builtin_amdgcn_mfma_f32_16x16x32_bf16(k0, qfA, z, 0, 0, 0);
            f32x4 cA1 = __builtin_amdgcn_mfma_f32_16x16x32_bf16(k1, qfA, z, 0, 0, 0);
            f32x4 cB0 = __builtin_amdgcn_mfma_f32_16x16x32_bf16(k0, qfB, z, 0, 0, 0);
            f32x4 cB1 = __builtin_amdgcn_mfma_f32_16x16x32_bf16(k1, qfB, z, 0, 0, 0);
            const int col = hf * 32 + 8 * g;
            const f32x4 gA0 = *(const f32x4*)&cmb[ql * CS + col];
            const f32x4 gA1 = *(const f32x4*)&cmb[ql * CS + col + 4];
            const f32x4 gB0 = *(const f32x4*)&cmb[(ql + 16) * CS + col];
            const f32x4 gB1 = *(const f32x4*)&cmb[(ql + 16) * CS + col + 4];
            #pragma unroll
            for (int j = 0; j < 4; ++j) {
                cA0[j] = __builtin_amdgcn_exp2f(cA0[j] + gA0[j]);
                cA1[j] = __builtin_amdgcn_exp2f(cA1[j] + gA1[j]);
                cB0[j] = __builtin_amdgcn_exp2f(cB0[j] + gB0[j]);
                cB1[j] = __builtin_amdgcn_exp2f(cB1[j] + gB1[j]);
                ssA += cA0[j] + cA1[j];
                ssB += cB0[j] + cB1[j];
            }
            union { unsigned u[4]; bf16x8 v; } pfA, pfB;
            pfA.u[0] = pk2(cA0[0], cA0[1]);  pfA.u[1] = pk2(cA0[2], cA0[3]);
            pfA.u[2] = pk2(cA1[0], cA1[1]);  pfA.u[3] = pk2(cA1[2], cA1[3]);
            pfB.u[0] = pk2(cB0[0], cB0[1]);  pfB.u[1] = pk2(cB0[2], cB0[3]);
            pfB.u[2] = pk2(cB1[0], cB1[1]);  pfB.u[3] = pk2(cB1[2], cB1[3]);
            const bf16x8 vf = *(const bf16x8*)(vbase + kb + 8 * g);   // shared by A and B
            accA = __builtin_amdgcn_mfma_f32_16x16x32_bf16(vf, pfA.v, accA, 0, 0, 0);
            accB = __builtin_amdgcn_mfma_f32_16x16x32_bf16(vf, pfB.v, accB, 0, 0, 0);
        }
        if (kt + 1 < KT) {               // blend + write the OTHER buffer (disjoint from reads)
            float* dst = lds + ((kt + 1) & 1) * (QB * CS);
            *(f32x4*)&dst[sq * CS + sk]     = fre * l0 + ofre * f0;
            *(f32x4*)&dst[sq * CS + sk + 4] = fre * l1 + ofre * f1;
        }
    }

    // per-query sum of exps
    ssA += __shfl_xor(ssA, 16);  ssA += __shfl_xor(ssA, 32);
    ssB += __shfl_xor(ssB, 16);  ssB += __shfl_xor(ssB, 32);
    if (g == 0) {
        psum[((size_t)(split * BB + b) * NH + hw) * NN + qb + ql] = ssA;
        psum[((size_t)(split * BB + b) * NH + hw) * NN + qb + 16 + ql] = ssB;
    }

    // unnormalized partial context -> transpose via buf0-as-ldsO (disjoint from final
    // phase's buf1 reads; all buf0 reads were fenced by the kt=KT-1 barrier)
    float* ldsO = lds;                    // [32][CS]
    #pragma unroll
    for (int j = 0; j < 4; ++j) {
        ldsO[ql * CS + hw * 16 + 4 * g + j] = accA[j];
        ldsO[(ql + 16) * CS + hw * 16 + 4 * g + j] = accB[j];
    }
    __syncthreads();
    {
        const int r = t >> 3, c = (t & 7) * 8;
        const f32x4 o0 = *(const f32x4*)&ldsO[r * CS + c];
        const f32x4 o1 = *(const f32x4*)&ldsO[r * CS + c + 4];
        float* prow = pacc + ((size_t)(split * BB + b) * NN + qb + r) * FD + c;
        *(f32x4*)prow = o0;
        *(f32x4*)(prow + 4) = o1;
    }
}

// ---------------- Pass C: combine splits, out = LN(ctx @ W2 + b2 + residual)
__global__ __launch_bounds__(256) void out_kernel(
    const float* __restrict__ pacc, const float* __restrict__ psum,
    const float* __restrict__ feat,
    const float* __restrict__ W2, const float* __restrict__ b2,
    const float* __restrict__ lng, const float* __restrict__ lnb,
    float* __restrict__ out)
{
    __shared__ float cl[4][64];
    const int t = threadIdx.x;
    const int w = t >> 6, d = t & 63;
    const int node = blockIdx.x * 4 + w;
    const int b = node >> 11, n = node & (NN - 1);
    const int h = d >> 4;

    float a = 0.f, sh = 0.f;
    #pragma unroll
    for (int sp = 0; sp < SPLIT; ++sp) {
        a  += pacc[((size_t)sp * BB * NN + node) * FD + d];
        sh += psum[((size_t)(sp * BB + b) * NH + h) * NN + n];
    }
    cl[w][d] = a / sh;
    __syncthreads();

    float o = b2[d];
    #pragma unroll 8
    for (int dd = 0; dd < 64; ++dd) o += cl[w][dd] * W2[dd * 64 + d];
    o += feat[(size_t)node * FD + d];

    const float mu = wsum(o) * (1.f / 64.f);
    const float df = o - mu;
    const float va = wsum(df * df) * (1.f / 64.f);
    out[(size_t)node * FD + d] = df * rsqrtf(va + 1e-5f) * lng[d] + lnb[d];
    if (blockIdx.x == 0 && t == 0)
        out[(size_t)BB * NN * FD] = 4.8828125e-9f;  // 1e-5 * mean(attn) = 1e-5 / N exactly
}

extern "C" void kernel_launch(void* const* d_in, const int* in_sizes, int n_in,
                              void* d_out, int out_size, void* d_ws, size_t ws_size,
                              hipStream_t stream) {
    const float* feat   = (const float*)d_in[0];
    const float* fixedg = (const float*)d_in[1];
    const float* learng = (const float*)d_in[2];
    const float* Wqc = (const float*)d_in[3];
    const float* bqc = (const float*)d_in[4];
    const float* Wqe = (const float*)d_in[5];
    const float* bqe = (const float*)d_in[6];
    const float* Woc = (const float*)d_in[7];
    const float* boc = (const float*)d_in[8];
    const float* Woe = (const float*)d_in[9];
    const float* boe = (const float*)d_in[10];
    const float* bf1 = (const float*)d_in[11];
    const float* bf2 = (const float*)d_in[12];
    const float* gfus = (const float*)d_in[13];
    const float* lng = (const float*)d_in[14];
    const float* lnb = (const float*)d_in[15];

    char* ws = (char*)d_ws;
    __hip_bfloat16* Qe = (__hip_bfloat16*)ws;                       // 2 MB
    __hip_bfloat16* Ke = Qe + (size_t)BB * NH * NN * 32;            // 2 MB
    __hip_bfloat16* Vt = Ke + (size_t)BB * NH * NN * 32;            // 1 MB
    float* pacc = (float*)(Vt + (size_t)BB * NH * HDD * NN);        // SPLIT*B*N*64 f32 = 16.8 MB
    float* psum = pacc + (size_t)SPLIT * BB * NN * FD;              // 1 MB
    float* W1 = psum + (size_t)SPLIT * BB * NH * NN;                // 48 KB
    float* b1 = W1 + 64 * 192;
    float* W2 = b1 + 192;                                           // 16 KB
    float* b2 = W2 + 64 * 64;
    float* out = (float*)d_out;

    hipLaunchKernelGGL(fuse_kernel, dim3(2), dim3(256), 0, stream,
                       Wqc, bqc, Wqe, bqe, Woc, boc, Woe, boe, W1, b1, W2, b2);
    hipLaunchKernelGGL(qkv_kernel, dim3(BB * NN / 4), dim3(256), 0, stream,
                       feat, W1, b1, bf1, bf2, Qe, Ke, Vt);
    hipLaunchKernelGGL(attn_kernel, dim3(BB * (NN / QB) * SPLIT), dim3(256), 0, stream,
                       fixedg, learng, gfus, Qe, Ke, Vt, pacc, psum);
    hipLaunchKernelGGL(out_kernel, dim3(BB * NN / 4), dim3(256), 0, stream,
                       pacc, psum, feat, W2, b2, lng, lnb, out);
}